// Round 2
// baseline (483.827 us; speedup 1.0000x reference)
//
#include <hip/hip_runtime.h>

// Problem constants (from reference)
#define N_SPARSE 16
#define N_SEQ    2
#define N_DENSE  13
#define VOCAB    100000
#define EMBED    64
#define SEQ_LEN  50
#define BATCH    4096
#define N_FEAT   (N_SPARSE + N_SEQ)          // 18
#define OUT_COLS (N_FEAT * EMBED + N_DENSE)  // 1165

typedef float f4v __attribute__((ext_vector_type(4)));  // native vec for nontemporal

// Block layout:
//  - blocks [0, 4096):   one block per batch row b; 4 waves = (sf,half) pairs,
//                        each wave pools 25 seq rows with ALL loads issued
//                        before any accumulation (max memory-level parallelism).
//  - blocks [4096, 5120): sparse gather + dense copy, one wave per b (4 b/block).
#define SEQ_BLOCKS BATCH            // 4096
#define SB_BLOCKS  (BATCH / 4)      // 1024
#define NBLOCKS    (SEQ_BLOCKS + SB_BLOCKS)

__global__ __launch_bounds__(256) void emb_kernel(
    const float* __restrict__ sparse_tables,  // [16,100000,64]
    const float* __restrict__ seq_tables,     // [2,100000,64]
    const float* __restrict__ dense_vals,     // [4096,13]
    const int* __restrict__ sparse_idx,       // [16,4096]
    const int* __restrict__ seq_idx,          // [2,4096,50]
    float* __restrict__ out)                  // [4096,1165]
{
    const int tid  = threadIdx.x;
    const int lane = tid & 63;
    const int wv   = tid >> 6;       // wave in block, 0..3
    const int g    = lane >> 4;      // lane group 0..3 (one row per group)
    const int l16  = lane & 15;      // position within group (float4 -> 64 cols)

    if (blockIdx.x < SEQ_BLOCKS) {
        // ---------------- sequence pooling: one block per b ----------------
        __shared__ float s_sum[4][EMBED];
        __shared__ float s_cnt[4][EMBED];

        const int b  = blockIdx.x;
        const int sf = wv >> 1;      // 0 = sum pool, 1 = mean pool
        const int h  = wv & 1;       // half: rows [h*25, h*25+25)

        const int* ip = seq_idx + ((size_t)(sf * BATCH + b)) * SEQ_LEN;
        int myidx = (lane < SEQ_LEN) ? ip[lane] : 0;   // lane s holds index of row s
        const float* tab = seq_tables + (size_t)sf * VOCAB * EMBED;

        // Phase 1: broadcast all 7 row indices for this wave's rounds.
        int ridx[7];
        #pragma unroll
        for (int i = 0; i < 7; ++i)
            ridx[i] = __shfl(myidx, h * 25 + i * 4 + g);   // src<=52, ok

        // Phase 2: issue ALL gathers back-to-back (no accumulate in between).
        float4 v[7];
        #pragma unroll
        for (int i = 0; i < 7; ++i) {
            const int rl = i * 4 + g;                       // 0..27
            if (rl < 25)
                v[i] = *reinterpret_cast<const float4*>(
                    tab + (size_t)ridx[i] * EMBED + 4 * l16);
            else
                v[i] = make_float4(0.f, 0.f, 0.f, 0.f);     // padding round
        }

        // Phase 3: accumulate sums + nonzero counts.
        float ax = 0.f, ay = 0.f, az = 0.f, aw = 0.f;
        float cx = 0.f, cy = 0.f, cz = 0.f, cw = 0.f;
        #pragma unroll
        for (int i = 0; i < 7; ++i) {
            ax += v[i].x; ay += v[i].y; az += v[i].z; aw += v[i].w;
            cx += (v[i].x != 0.f) ? 1.f : 0.f;
            cy += (v[i].y != 0.f) ? 1.f : 0.f;
            cz += (v[i].z != 0.f) ? 1.f : 0.f;
            cw += (v[i].w != 0.f) ? 1.f : 0.f;
        }

        // Reduce partial sums across the 4 lane groups (xor 16, then 32).
        ax += __shfl_xor(ax, 16); ax += __shfl_xor(ax, 32);
        ay += __shfl_xor(ay, 16); ay += __shfl_xor(ay, 32);
        az += __shfl_xor(az, 16); az += __shfl_xor(az, 32);
        aw += __shfl_xor(aw, 16); aw += __shfl_xor(aw, 32);
        cx += __shfl_xor(cx, 16); cx += __shfl_xor(cx, 32);
        cy += __shfl_xor(cy, 16); cy += __shfl_xor(cy, 32);
        cz += __shfl_xor(cz, 16); cz += __shfl_xor(cz, 32);
        cw += __shfl_xor(cw, 16); cw += __shfl_xor(cw, 32);

        if (lane < 16) {
            float4* ss = reinterpret_cast<float4*>(&s_sum[wv][4 * l16]);
            float4* sc = reinterpret_cast<float4*>(&s_cnt[wv][4 * l16]);
            *ss = make_float4(ax, ay, az, aw);
            *sc = make_float4(cx, cy, cz, cw);
        }
        __syncthreads();

        // Combine halves + write: threads 0..127 cover (sf, col).
        if (tid < 2 * EMBED) {
            const int osf = tid >> 6;     // 0 or 1
            const int c   = tid & 63;
            float s = s_sum[2 * osf][c] + s_sum[2 * osf + 1][c];
            if (osf == 1) {
                const float cnt = s_cnt[2][c] + s_cnt[3][c];
                s = s / (cnt + 1e-16f);
            }
            out[(size_t)b * OUT_COLS + (N_SPARSE + osf) * EMBED + c] = s;
        }
    } else {
        // -------- sparse gather (16 features) + dense copy: one wave per b --------
        const int b = (blockIdx.x - SEQ_BLOCKS) * 4 + wv;
        // lanes 0..15 fetch the 16 feature indices, broadcast via shfl
        int myidx16 = (lane < N_SPARSE) ? sparse_idx[lane * BATCH + b] : 0;

        f4v v[4];
        #pragma unroll
        for (int i = 0; i < 4; ++i) {
            const int f   = i * 4 + g;
            const int idx = __shfl(myidx16, f);
            // zero-reuse rows: nontemporal to avoid polluting L2/L3
            v[i] = __builtin_nontemporal_load(
                reinterpret_cast<const f4v*>(
                    sparse_tables + ((size_t)f * VOCAB + idx) * EMBED + 4 * l16));
        }
        float* ob = out + (size_t)b * OUT_COLS;
        #pragma unroll
        for (int i = 0; i < 4; ++i) {
            const int f = i * 4 + g;
            float* o = ob + f * EMBED + 4 * l16;
            o[0] = v[i].x; o[1] = v[i].y; o[2] = v[i].z; o[3] = v[i].w;
        }
        // dense passthrough: 13 floats per batch row
        if (lane < N_DENSE)
            ob[N_FEAT * EMBED + lane] = dense_vals[b * N_DENSE + lane];
    }
}

extern "C" void kernel_launch(void* const* d_in, const int* in_sizes, int n_in,
                              void* d_out, int out_size, void* d_ws, size_t ws_size,
                              hipStream_t stream) {
    const float* sparse_tables = (const float*)d_in[0];
    const float* seq_tables    = (const float*)d_in[1];
    const float* dense_vals    = (const float*)d_in[2];
    const int*   sparse_idx    = (const int*)d_in[3];
    const int*   seq_idx       = (const int*)d_in[4];
    float*       out           = (float*)d_out;

    emb_kernel<<<dim3(NBLOCKS), dim3(256), 0, stream>>>(
        sparse_tables, seq_tables, dense_vals, sparse_idx, seq_idx, out);
}